// Round 2
// 1005.509 us; speedup vs baseline: 1.0054x; 1.0054x over previous
//
#include <hip/hip_runtime.h>

// PoissonPinn, round-5 (resubmit — round-5 never ran: container infra failure).
// Orientation-flipped MFMA chain.
//
// Diagnosis from round-4 counters: MfmaUtil(47.3) + VALUBusy(52.6) = 99.9 and
// achieved MFMA TF = 47.3% of the 16x16x32 ceiling => VALUBusy includes the
// MFMA class; true VALU ~5%, ~47% of cycles IDLE (phase serialization:
// epilogues / b16 LDS scatters / barriers leave the matrix pipe empty).
//
// Round-5 changes:
//  * GEMMs computed as D[n][p] = W^T * H (weights = A-operand, activations =
//    B-operand). With C-layout col=lane&15 (=p), row=(lane>>4)*4+reg (=n),
//    each lane's epilogue output IS the next layer's B-fragment for the two
//    "own" K-chunks (k-slot permutation k = 32ks + 16(j>>2) + 4q + (j&3)
//    baked into prep_w on both operands). 72 own-chunk MFMAs issue BEFORE the
//    barrier and drain during it.
//  * LDS H exchange is [p][k] with packed b64 writes (24/layer vs 96 b16) and
//    b64 fragment reads; 16-lane groups hit 16 distinct bank pairs.
//  * Layer-3: no split/no LDS write; s-channel finishes register-direct into
//    the W4 dot (shfl_xor over q + 256B cross-wave reduce). One barrier and
//    the whole final-LDS phase deleted.
//  * s_setprio(1) around MFMA bursts (wave role-diversity now exists).

constexpr int HID   = 256;
constexpr int MPTS  = 16;              // points per block (eq kernel)
constexpr int SK    = 260;             // LDS row stride in bf16 elems (520B, 8B-aligned)
constexpr int WELEM = 3 * HID * HID;

typedef __bf16 bf16x8 __attribute__((ext_vector_type(8)));
typedef __bf16 bf16x4 __attribute__((ext_vector_type(4)));
typedef float  f32x4  __attribute__((ext_vector_type(4)));

__device__ __forceinline__ float fast_tanh(float x) {
    float e = __expf(2.0f * x);
    return 1.0f - 2.0f / (e + 1.0f);
}

// ---- prep: W1..W3 (fp32 [k][n]) -> bf16 hi/lo, A-fragment order for the
// flipped orientation. Layout Wf[l][NT(16)][ks(8)][lane(64)][j(8)]:
// lane = q*16+m supplies A[n = NT*16+m][slot j] = W[k][n] with
// k = 32*ks + 16*(j>>2) + 4*q + (j&3)  (the slot permutation; must match the
// B-side reads below — it does, see loadB/PB packing).
__global__ void prep_w(const float* __restrict__ W1,
                       const float* __restrict__ W2,
                       const float* __restrict__ W3,
                       __bf16* __restrict__ Wh, __bf16* __restrict__ Wl) {
    const int idx = blockIdx.x * 256 + threadIdx.x;   // 0 .. WELEM-1
    const int l   = idx >> 16;
    const int r   = idx & 0xFFFF;
    const int NT  = r >> 12;
    const int ks  = (r >> 9) & 7;
    const int ln  = (r >> 3) & 63;
    const int j   = r & 7;
    const int q   = ln >> 4;
    const int mm  = ln & 15;
    const int k   = ks * 32 + ((j >> 2) << 4) + q * 4 + (j & 3);
    const int n   = NT * 16 + mm;
    const float* W = (l == 0) ? W1 : (l == 1) ? W2 : W3;
    const float w  = W[k * HID + n];
    const __bf16 hi = (__bf16)w;
    Wh[idx] = hi;
    Wl[idx] = (__bf16)(w - (float)hi);
}

__global__ __launch_bounds__(256, 2)
void pinn_eq_mfma(const float* __restrict__ x,
                  const float* __restrict__ W0, const float* __restrict__ b0,
                  const float* __restrict__ b1, const float* __restrict__ b2,
                  const float* __restrict__ b3, const float* __restrict__ W4,
                  const __bf16* __restrict__ Wh, const __bf16* __restrict__ Wl,
                  float* __restrict__ out)
{
    // H exchange: [ch*2+part][p][k], ch in {v,d,s}, part in {hi,lo}
    __shared__ __align__(16) __bf16 Hls[6][MPTS][SK];   // 49920 B
    __shared__ float red[4][16];                        // cross-wave d2u reduce

    const int tid  = threadIdx.x;
    const int lane = tid & 63;
    const int wv   = tid >> 6;
    const int m    = lane & 15;     // = p (output col / B-frag col)
    const int q    = lane >> 4;
    const int pb   = blockIdx.x * MPTS;

    f32x4 acc[3][4];                               // [ch][nt]
    bf16x8 AH0[4], AL0[4], AH1[4], AL1[4];         // weight frags (dbuf)
    bf16x8 BH0[3], BL0[3], BH1[3], BL1[3];         // activation frags (dbuf)

    auto zacc = [&]() {
        #pragma unroll
        for (int ch = 0; ch < 3; ++ch)
            #pragma unroll
            for (int nt = 0; nt < 4; ++nt)
                acc[ch][nt] = (f32x4)0.0f;
    };
    auto loadA = [&](bf16x8 (&AH)[4], bf16x8 (&AL)[4],
                     const __bf16* wh, const __bf16* wl, int ks) {
        #pragma unroll
        for (int nt = 0; nt < 4; ++nt) {
            const int off = (((wv * 4 + nt) * 8 + ks) * 64 + lane) * 8;
            AH[nt] = *(const bf16x8*)(wh + off);
            AL[nt] = *(const bf16x8*)(wl + off);
        }
    };
    auto loadB = [&](bf16x8 (&BH)[3], bf16x8 (&BL)[3], int ks) {
        const int kb = ks * 32 + q * 4;
        #pragma unroll
        for (int ch = 0; ch < 3; ++ch) {
            const bf16x4 h0 = *(const bf16x4*)&Hls[ch * 2    ][m][kb];
            const bf16x4 h1 = *(const bf16x4*)&Hls[ch * 2    ][m][kb + 16];
            const bf16x4 l0 = *(const bf16x4*)&Hls[ch * 2 + 1][m][kb];
            const bf16x4 l1 = *(const bf16x4*)&Hls[ch * 2 + 1][m][kb + 16];
            BH[ch] = __builtin_shufflevector(h0, h1, 0, 1, 2, 3, 4, 5, 6, 7);
            BL[ch] = __builtin_shufflevector(l0, l1, 0, 1, 2, 3, 4, 5, 6, 7);
        }
    };
    auto mfma36 = [&](const bf16x8 (&AH)[4], const bf16x8 (&AL)[4],
                      const bf16x8 (&BH)[3], const bf16x8 (&BL)[3]) {
        __builtin_amdgcn_s_setprio(1);
        #pragma unroll
        for (int ch = 0; ch < 3; ++ch)
            #pragma unroll
            for (int nt = 0; nt < 4; ++nt)
                acc[ch][nt] = __builtin_amdgcn_mfma_f32_16x16x32_bf16(AH[nt], BH[ch], acc[ch][nt], 0, 0, 0);
        #pragma unroll
        for (int ch = 0; ch < 3; ++ch)
            #pragma unroll
            for (int nt = 0; nt < 4; ++nt)
                acc[ch][nt] = __builtin_amdgcn_mfma_f32_16x16x32_bf16(AH[nt], BL[ch], acc[ch][nt], 0, 0, 0);
        #pragma unroll
        for (int ch = 0; ch < 3; ++ch)
            #pragma unroll
            for (int nt = 0; nt < 4; ++nt)
                acc[ch][nt] = __builtin_amdgcn_mfma_f32_16x16x32_bf16(AL[nt], BH[ch], acc[ch][nt], 0, 0, 0);
        __builtin_amdgcn_s_setprio(0);
    };

    // ---- layer 0: thread -> point p = tid&15, cols cg..cg+15 ----
    {
        const int p  = tid & 15;
        const int cg = (tid >> 4) * 16;
        const float xv = x[pb + p];
        float vv[16], dd[16], ss[16];
        #pragma unroll
        for (int cc = 0; cc < 16; ++cc) {
            const int c = cg + cc;
            const float w  = W0[c];
            const float bb = b0[c];
            const float v  = fast_tanh(fmaf(xv, w, bb));
            const float s2 = 1.0f - v * v;
            vv[cc] = v;
            dd[cc] = s2 * w;
            ss[cc] = -2.0f * v * s2 * w * w;
        }
        auto packwrite = [&](const float (&a)[16], int cp) {
            #pragma unroll
            for (int g = 0; g < 4; ++g) {
                bf16x4 h, lo;
                #pragma unroll
                for (int e = 0; e < 4; ++e) {
                    const float fv = a[g * 4 + e];
                    const __bf16 hh = (__bf16)fv;
                    h[e]  = hh;
                    lo[e] = (__bf16)(fv - (float)hh);
                }
                *(bf16x4*)&Hls[cp    ][p][cg + g * 4] = h;
                *(bf16x4*)&Hls[cp + 1][p][cg + g * 4] = lo;
            }
        };
        packwrite(vv, 0);
        packwrite(dd, 2);
        packwrite(ss, 4);
    }
    __syncthreads();

    // ---- GEMM layer 1 (W1): all 8 K-chunks from LDS, dbuf pipeline ----
    zacc();
    loadA(AH0, AL0, Wh, Wl, 0);
    loadB(BH0, BL0, 0);
    #pragma unroll 1
    for (int it = 0; it < 4; ++it) {
        const int ks = it * 2;
        loadA(AH1, AL1, Wh, Wl, ks + 1);
        loadB(BH1, BL1, ks + 1);
        mfma36(AH0, AL0, BH0, BL0);
        if (it < 3) {
            loadA(AH0, AL0, Wh, Wl, ks + 2);
            loadB(BH0, BL0, ks + 2);
        }
        mfma36(AH1, AL1, BH1, BL1);
    }

    // ---- transitions: epilogue(l) -> own-chunk MFMAs(l+1) -> exchange -> 6 chunks ----
    #pragma unroll 1
    for (int l = 0; l < 2; ++l) {
        const __bf16* whN = Wh + (l + 1) * (HID * HID);
        const __bf16* wlN = Wl + (l + 1) * (HID * HID);
        const float* bl = (l == 0) ? b1 : b2;

        // prefetch next layer's own-chunk weight frags; epilogue hides L2 latency
        loadA(AH0, AL0, whN, wlN, 2 * wv);
        loadA(AH1, AL1, whN, wlN, 2 * wv + 1);

        // jet epilogue; hi/lo split packed directly in next-layer B-frag order:
        // PH[ch][c] elem (t*4+r)  <->  k = 64*wv + 32*c + 16*t + 4*q + r
        bf16x8 PH[3][2], PL[3][2];
        #pragma unroll
        for (int c = 0; c < 2; ++c)
            #pragma unroll
            for (int t = 0; t < 2; ++t) {
                const int nt = c * 2 + t;
                #pragma unroll
                for (int r = 0; r < 4; ++r) {
                    const int n  = (wv * 4 + nt) * 16 + q * 4 + r;
                    const float zv = acc[0][nt][r] + bl[n];
                    const float zd = acc[1][nt][r];
                    const float zs = acc[2][nt][r];
                    const float v  = fast_tanh(zv);
                    const float s2 = 1.0f - v * v;
                    const float dn = s2 * zd;
                    const float sn = s2 * zs - 2.0f * v * s2 * zd * zd;
                    const int e = t * 4 + r;
                    { const __bf16 h = (__bf16)v;  PH[0][c][e] = h; PL[0][c][e] = (__bf16)(v  - (float)h); }
                    { const __bf16 h = (__bf16)dn; PH[1][c][e] = h; PL[1][c][e] = (__bf16)(dn - (float)h); }
                    { const __bf16 h = (__bf16)sn; PH[2][c][e] = h; PL[2][c][e] = (__bf16)(sn - (float)h); }
                }
            }

        zacc();
        // own-chunk MFMAs (register-direct B): drain during the barrier wait
        {
            bf16x8 bh[3] = {PH[0][0], PH[1][0], PH[2][0]};
            bf16x8 bo[3] = {PL[0][0], PL[1][0], PL[2][0]};
            mfma36(AH0, AL0, bh, bo);
        }
        {
            bf16x8 bh[3] = {PH[0][1], PH[1][1], PH[2][1]};
            bf16x8 bo[3] = {PL[0][1], PL[1][1], PL[2][1]};
            mfma36(AH1, AL1, bh, bo);
        }
        __syncthreads();   // all waves done READING previous H
        // write own 64-col k-slice, packed b64
        #pragma unroll
        for (int ch = 0; ch < 3; ++ch)
            #pragma unroll
            for (int c = 0; c < 2; ++c) {
                const int k0 = wv * 64 + c * 32 + q * 4;
                *(bf16x4*)&Hls[ch * 2    ][m][k0]      = __builtin_shufflevector(PH[ch][c], PH[ch][c], 0, 1, 2, 3);
                *(bf16x4*)&Hls[ch * 2 + 1][m][k0]      = __builtin_shufflevector(PL[ch][c], PL[ch][c], 0, 1, 2, 3);
                *(bf16x4*)&Hls[ch * 2    ][m][k0 + 16] = __builtin_shufflevector(PH[ch][c], PH[ch][c], 4, 5, 6, 7);
                *(bf16x4*)&Hls[ch * 2 + 1][m][k0 + 16] = __builtin_shufflevector(PL[ch][c], PL[ch][c], 4, 5, 6, 7);
            }
        loadA(AH0, AL0, whN, wlN, (2 * wv + 2) & 7);   // prefetch first LDS chunk's A
        __syncthreads();   // writes visible
        loadB(BH0, BL0, (2 * wv + 2) & 7);
        #pragma unroll 1
        for (int it = 0; it < 3; ++it) {
            const int kb = (2 * wv + 3 + 2 * it) & 7;
            loadA(AH1, AL1, whN, wlN, kb);
            loadB(BH1, BL1, kb);
            mfma36(AH0, AL0, BH0, BL0);
            if (it < 2) {
                const int kc = (2 * wv + 4 + 2 * it) & 7;
                loadA(AH0, AL0, whN, wlN, kc);
                loadB(BH0, BL0, kc);
            }
            mfma36(AH1, AL1, BH1, BL1);
        }
    }

    // ---- layer 3 finish: s-channel register-direct into W4 dot ----
    {
        float P = 0.0f;
        #pragma unroll
        for (int nt = 0; nt < 4; ++nt)
            #pragma unroll
            for (int r = 0; r < 4; ++r) {
                const int n  = (wv * 4 + nt) * 16 + q * 4 + r;
                const float zv = acc[0][nt][r] + b3[n];
                const float zd = acc[1][nt][r];
                const float zs = acc[2][nt][r];
                const float v  = fast_tanh(zv);
                const float s2 = 1.0f - v * v;
                const float sn = s2 * zs - 2.0f * v * s2 * zd * zd;
                P = fmaf(sn, W4[n], P);
            }
        P += __shfl_xor(P, 16, 64);
        P += __shfl_xor(P, 32, 64);
        if (q == 0) red[wv][m] = P;
        __syncthreads();
        if (tid < 16)
            out[pb + tid] = red[0][tid] + red[1][tid] + red[2][tid] + red[3][tid];
    }
}

// ---- boundary: plain fp32 vector forward (tiny: 8192 points) ----
constexpr int BPW = 4;
constexpr int BP  = 16;

__global__ __launch_bounds__(256, 3)
void pinn_bnd_kernel(const float* __restrict__ x,
                     const float* __restrict__ W0, const float* __restrict__ b0,
                     const float* __restrict__ W1, const float* __restrict__ b1,
                     const float* __restrict__ W2, const float* __restrict__ b2,
                     const float* __restrict__ W3, const float* __restrict__ b3,
                     const float* __restrict__ W4, const float* __restrict__ b4,
                     float* __restrict__ out)
{
    __shared__ float HV[BP][HID];

    const int lane  = threadIdx.x & 63;
    const int wv    = threadIdx.x >> 6;
    const int rbase = wv * BPW;
    const int pbase = blockIdx.x * BP + rbase;

    #pragma unroll
    for (int c = 0; c < 4; ++c) {
        const int   j  = lane + 64 * c;
        const float w  = W0[j];
        const float bb = b0[j];
        #pragma unroll
        for (int p = 0; p < BPW; ++p)
            HV[rbase + p][j] = fast_tanh(x[pbase + p] * w + bb);
    }
    __syncthreads();

    const float* Ws[3] = {W1, W2, W3};
    const float* bs[3] = {b1, b2, b3};

    #pragma unroll
    for (int l = 0; l < 3; ++l) {
        const float* __restrict__ W = Ws[l];
        const float* __restrict__ b = bs[l];

        float zv[BPW][4];
        #pragma unroll
        for (int p = 0; p < BPW; ++p)
            #pragma unroll
            for (int c = 0; c < 4; ++c)
                zv[p][c] = b[lane + 64 * c];

        for (int i = 0; i < HID; i += 4) {
            float w[4][4];
            #pragma unroll
            for (int qq = 0; qq < 4; ++qq)
                #pragma unroll
                for (int c = 0; c < 4; ++c)
                    w[qq][c] = W[(i + qq) * HID + lane + 64 * c];

            #pragma unroll
            for (int p = 0; p < BPW; ++p) {
                const float4 av = *(const float4*)&HV[rbase + p][i];
                #pragma unroll
                for (int qq = 0; qq < 4; ++qq) {
                    const float a_v = ((const float*)&av)[qq];
                    #pragma unroll
                    for (int c = 0; c < 4; ++c)
                        zv[p][c] = fmaf(a_v, w[qq][c], zv[p][c]);
                }
            }
        }
        __syncthreads();

        #pragma unroll
        for (int p = 0; p < BPW; ++p)
            #pragma unroll
            for (int c = 0; c < 4; ++c)
                HV[rbase + p][lane + 64 * c] = fast_tanh(zv[p][c]);
        __syncthreads();
    }

    const float bias4 = b4[0];
    #pragma unroll
    for (int p = 0; p < BPW; ++p) {
        float acc = 0.0f;
        #pragma unroll
        for (int c = 0; c < 4; ++c) {
            const int j = lane + 64 * c;
            acc = fmaf(HV[rbase + p][j], W4[j], acc);
        }
        #pragma unroll
        for (int off = 32; off > 0; off >>= 1)
            acc += __shfl_down(acc, off, 64);
        if (lane == 0) out[pbase + p] = acc + bias4;
    }
}

extern "C" void kernel_launch(void* const* d_in, const int* in_sizes, int n_in,
                              void* d_out, int out_size, void* d_ws, size_t ws_size,
                              hipStream_t stream) {
    const float* xe = (const float*)d_in[0];
    const float* xb = (const float*)d_in[1];
    const float* W0 = (const float*)d_in[2];
    const float* b0 = (const float*)d_in[3];
    const float* W1 = (const float*)d_in[4];
    const float* b1 = (const float*)d_in[5];
    const float* W2 = (const float*)d_in[6];
    const float* b2 = (const float*)d_in[7];
    const float* W3 = (const float*)d_in[8];
    const float* b3 = (const float*)d_in[9];
    const float* W4 = (const float*)d_in[10];
    const float* b4 = (const float*)d_in[11];
    float* out = (float*)d_out;

    const int n_eq = in_sizes[0];   // 262144
    const int n_b  = in_sizes[1];   // 8192

    __bf16* Wh = (__bf16*)d_ws;                    // 3*256*256 bf16
    __bf16* Wl = Wh + WELEM;

    prep_w<<<WELEM / 256, 256, 0, stream>>>(W1, W2, W3, Wh, Wl);

    pinn_eq_mfma<<<n_eq / MPTS, 256, 0, stream>>>(
        xe, W0, b0, b1, b2, b3, W4, Wh, Wl, out);

    pinn_bnd_kernel<<<n_b / BP, 256, 0, stream>>>(
        xb, W0, b0, W1, b1, W2, b2, W3, b3, W4, b4, out + n_eq);
}